// Round 12
// baseline (1241.199 us; speedup 1.0000x reference)
//
#include <hip/hip_runtime.h>

// ---------------------------------------------------------------------------
// TwoBranchFork: out = LN( concat(x@q(w_a)^T, x@q(w_b)^T) @ w_proj^T )
// Reassociated: W_eff = w_proj @ [q(w_a); q(w_b)]  (4096x4096), h = x @ W_eff^T
// Round 12: whole-tile read issue + counted-lgkm quadrant drains.
// Per K-tile (2 barriers):
//   issue ds: b01(4) |SB| a0(8) |SB| b23(4) |SB| a1(8) |SB|   (order pinned)
//   stage A0,A1(t+1)->saN
//   lgkm(12)|SB| Q1: acc[0..3][0,1] += a0*b01     (b23,a1 drain under Q1)
//   lgkm(8) |SB| Q2: acc[0..3][2,3] += a0*b23     (a1 drains under Q2)
//   BAR  -- every wave passed lgkm(8) => ALL waves' sb reads complete
//   stage B0,B1(t+2)->sb                           (WAR safe cross-wave)
//   lgkm(0) |SB| Q3: acc[4..7][2,3] += a1*b23 ; Q4: acc[4..7][0,1] += a1*b01
//   vmcnt(4|0)  -- drains B(t+1) [staged t-1 mid] + A(t+1) [staged t start],
//                  leaves B(t+2) in flight
//   BAR  -- tile boundary: t+1 operands proven resident for all waves; saN's
//          reads (a0/a1 of t-1) were drained at t-1's lgkm(0), barrier after.
// In-flight ledger (steady): enter t: B(t+1) 4. +A(t+1) 4 = 8. +B(t+2) 4 =12.
// vmcnt(4) drains oldest 8 = B(t+1),A(t+1) ✓. Edges: t+1>=NT no A stage;
// t+2>=NT no B stage, tail vmcnt(0). Prologue: A(0),B(0),B(1), vmcnt(4).
// Registers: operands 96 VGPR (same peak as r7's P3) + acc 128 AGPR.
// ---------------------------------------------------------------------------

typedef unsigned int u32;
typedef unsigned short u16;
typedef __bf16 bf16x8 __attribute__((ext_vector_type(8)));
typedef float f32x4 __attribute__((ext_vector_type(4)));
typedef u16 u16x8 __attribute__((ext_vector_type(8)));

#define AS1 __attribute__((address_space(1)))
#define AS3 __attribute__((address_space(3)))

__device__ __forceinline__ u16 f2bf(float f) {
  u32 u = __float_as_uint(f);
  u32 r = (u + 0x7fffu + ((u >> 16) & 1u)) >> 16;  // RNE
  return (u16)r;
}

// fp8 e4m3fn quantize-dequantize via HW cvt (OCP format + RNE on gfx950)
__device__ __forceinline__ float q_e4m3(float v) {
  int p = __builtin_amdgcn_cvt_pk_fp8_f32(v, v, 0, false);
  return __builtin_amdgcn_cvt_f32_fp8(p, 0);
}

__device__ __forceinline__ void gload16(const void* g, void* l) {
  __builtin_amdgcn_global_load_lds((const AS1 u32*)g, (AS3 u32*)l, 16, 0, 0);
}

// ---------------- elementwise f32 -> bf16 ----------------
__global__ __launch_bounds__(256) void k_f32_to_bf16(
    const float* __restrict__ in, u16* __restrict__ out, long n) {
  long i0 = ((long)blockIdx.x * 256 + threadIdx.x) * 8;
  long stride = (long)gridDim.x * 256 * 8;
  for (long i = i0; i < n; i += stride) {
    float4 a = *(const float4*)(in + i);
    float4 b = *(const float4*)(in + i + 4);
    u16x8 o;
    o[0] = f2bf(a.x); o[1] = f2bf(a.y); o[2] = f2bf(a.z); o[3] = f2bf(a.w);
    o[4] = f2bf(b.x); o[5] = f2bf(b.y); o[6] = f2bf(b.z); o[7] = f2bf(b.w);
    *(u16x8*)(out + i) = o;
  }
}

// ---------------- quantize (fp8 rt) + transpose into wqT ----------------
__global__ __launch_bounds__(256) void k_quant_transpose(
    const float* __restrict__ w, const float* __restrict__ s,
    u16* __restrict__ oT, int J, int Kd, int sCols, long oStride, int oColOff) {
  __shared__ u16 tile[64][72];
  int j0 = blockIdx.x * 64;
  int k0 = blockIdx.y * 64;
  float sc = s[(j0 >> 7) * sCols + (k0 >> 7)];
  int t = threadIdx.x;
  int row = t >> 2, seg = t & 3;
  const float4* src = (const float4*)(w + (long)(j0 + row) * Kd + k0 + seg * 16);
  u16* dst = &tile[row][seg * 16];
#pragma unroll
  for (int ii = 0; ii < 4; ++ii) {
    float4 v = src[ii];
    dst[ii * 4 + 0] = f2bf(q_e4m3(v.x / sc) * sc);
    dst[ii * 4 + 1] = f2bf(q_e4m3(v.y / sc) * sc);
    dst[ii * 4 + 2] = f2bf(q_e4m3(v.z / sc) * sc);
    dst[ii * 4 + 3] = f2bf(q_e4m3(v.w / sc) * sc);
  }
  __syncthreads();
  int r = t >> 2, cs = t & 3;
  u16* op = oT + (long)(k0 + r) * oStride + oColOff + j0 + cs * 16;
  u16x8 o0, o1;
#pragma unroll
  for (int ii = 0; ii < 8; ++ii) o0[ii] = tile[cs * 16 + ii][r];
#pragma unroll
  for (int ii = 0; ii < 8; ++ii) o1[ii] = tile[cs * 16 + 8 + ii][r];
  *(u16x8*)op = o0;
  *(u16x8*)(op + 8) = o1;
}

// ---------------- 256x256 bf16 bt-GEMM: C = A[M,K] * B[N,K]^T ---------------
template <bool OUT_BF16>
__global__ __launch_bounds__(512, 2) void k_gemm8(
    const u16* __restrict__ A, const u16* __restrict__ B, void* __restrict__ Cv,
    int M, int N, int K) {
  __shared__ u16 sAbuf[2][256 * 64];
  __shared__ u16 sBbuf[2][256 * 64];

  const int tid = threadIdx.x;
  const int lane = tid & 63;
  const int wave = tid >> 6;
  const int wr = wave >> 2, wc = wave & 3;  // 2x4 wave grid, each 128x64 of C

  // T1: XCD-aware block swizzle (grid % 8 == 0 by construction)
  const int nwg = gridDim.x;
  const int wg = blockIdx.x;
  const int wgs = (wg & 7) * (nwg >> 3) + (wg >> 3);
  const int nbn = N >> 8;
  const int m0 = (wgs / nbn) << 8;
  const int n0 = (wgs % nbn) << 8;
  const int NT = K >> 6;  // even for all our shapes (160, 64)

  const int lrow = lane & 15;
  const int kslot = lane >> 4;       // 0..3: 8-elem k-slot within 64-col row
  const int st_row = lane >> 3;      // staging: row within the 8-row stripe
  const int st_slot = lane & 7;
  const int st_src = ((st_slot ^ st_row) * 8);  // T2 inverse-swizzled source

  f32x4 acc[8][4] = {};

  auto stage = [&](const u16* __restrict__ G, int row0, u16* lds, int half,
                   int kt) {
#pragma unroll
    for (int r = 0; r < 2; ++r) {
      int row = half * 128 + r * 64 + wave * 8 + st_row;
      const u16* g = G + (long)(row0 + row) * K + kt * 64 + st_src;
      u16* l = lds + row * 64 + st_slot * 8;
      gload16(g, l);
    }
  };
  // T2 swizzled LDS fragment reads (2-way max bank aliasing = free)
  auto ldA = [&](const u16* sa, int mh, int m, int ks) -> bf16x8 {
    int row = wr * 128 + mh * 64 + m * 16 + lrow;
    int slot = (ks * 4 + kslot) ^ (row & 7);
    return *(const bf16x8*)(sa + row * 64 + slot * 8);
  };
  auto ldB = [&](const u16* sb, int n, int ks) -> bf16x8 {
    int row = wc * 64 + n * 16 + lrow;
    int slot = (ks * 4 + kslot) ^ (row & 7);
    return *(const bf16x8*)(sb + row * 64 + slot * 8);
  };

  // one K-tile: whole-tile read issue, counted-lgkm quadrant drains.
  auto ktile = [&](int t, const u16* sa, const u16* sb, u16* saN) {
    bf16x8 a0[4][2], a1[4][2], b01[2][2], b23[2][2];

    // ---- issue all 24 reads, order pinned: b01(4), a0(8), b23(4), a1(8)
#pragma unroll
    for (int n = 0; n < 2; ++n)
#pragma unroll
      for (int ks = 0; ks < 2; ++ks) b01[n][ks] = ldB(sb, n, ks);
    __builtin_amdgcn_sched_barrier(0);
#pragma unroll
    for (int m = 0; m < 4; ++m)
#pragma unroll
      for (int ks = 0; ks < 2; ++ks) a0[m][ks] = ldA(sa, 0, m, ks);
    __builtin_amdgcn_sched_barrier(0);
#pragma unroll
    for (int n = 0; n < 2; ++n)
#pragma unroll
      for (int ks = 0; ks < 2; ++ks) b23[n][ks] = ldB(sb, n + 2, ks);
    __builtin_amdgcn_sched_barrier(0);
#pragma unroll
    for (int m = 0; m < 4; ++m)
#pragma unroll
      for (int ks = 0; ks < 2; ++ks) a1[m][ks] = ldA(sa, 1, m, ks);
    __builtin_amdgcn_sched_barrier(0);

    // ---- stage A(t+1) into other-parity A buffer
    if (t + 1 < NT) {
      stage(A, m0, saN, 0, t + 1);
      stage(A, m0, saN, 1, t + 1);
    }

    // ---- Q1: needs b01+a0 (first 12); b23+a1 drain underneath
    asm volatile("s_waitcnt lgkmcnt(12)");
    __builtin_amdgcn_sched_barrier(0);
    __builtin_amdgcn_s_setprio(1);
#pragma unroll
    for (int m = 0; m < 4; ++m)
#pragma unroll
      for (int n = 0; n < 2; ++n)
#pragma unroll
        for (int ks = 0; ks < 2; ++ks)
          acc[m][n] = __builtin_amdgcn_mfma_f32_16x16x32_bf16(
              a0[m][ks], b01[n][ks], acc[m][n], 0, 0, 0);
    __builtin_amdgcn_s_setprio(0);

    // ---- Q2: needs b23 (first 16); a1 drains underneath
    asm volatile("s_waitcnt lgkmcnt(8)");
    __builtin_amdgcn_sched_barrier(0);
    __builtin_amdgcn_s_setprio(1);
#pragma unroll
    for (int m = 0; m < 4; ++m)
#pragma unroll
      for (int n = 0; n < 2; ++n)
#pragma unroll
        for (int ks = 0; ks < 2; ++ks)
          acc[m][n + 2] = __builtin_amdgcn_mfma_f32_16x16x32_bf16(
              a0[m][ks], b23[n][ks], acc[m][n + 2], 0, 0, 0);
    __builtin_amdgcn_s_setprio(0);

    // ---- mid barrier: every wave passed lgkm(8) => all sb reads complete
    __builtin_amdgcn_s_barrier();
    if (t + 2 < NT) {
      stage(B, n0, (u16*)sb, 0, t + 2);
      stage(B, n0, (u16*)sb, 1, t + 2);
    }

    // ---- Q3 + Q4 (a1 drained by lgkm(0); b01 still live)
    asm volatile("s_waitcnt lgkmcnt(0)");
    __builtin_amdgcn_sched_barrier(0);
    __builtin_amdgcn_s_setprio(1);
#pragma unroll
    for (int m = 0; m < 4; ++m)
#pragma unroll
      for (int n = 0; n < 2; ++n)
#pragma unroll
        for (int ks = 0; ks < 2; ++ks)
          acc[4 + m][n + 2] = __builtin_amdgcn_mfma_f32_16x16x32_bf16(
              a1[m][ks], b23[n][ks], acc[4 + m][n + 2], 0, 0, 0);
#pragma unroll
    for (int m = 0; m < 4; ++m)
#pragma unroll
      for (int n = 0; n < 2; ++n)
#pragma unroll
        for (int ks = 0; ks < 2; ++ks)
          acc[4 + m][n] = __builtin_amdgcn_mfma_f32_16x16x32_bf16(
              a1[m][ks], b01[n][ks], acc[4 + m][n], 0, 0, 0);
    __builtin_amdgcn_s_setprio(0);

    // ---- tile boundary: drain t+1 operands (leaves B(t+2) in flight)
    if (t + 2 < NT)
      asm volatile("s_waitcnt vmcnt(4)" ::: "memory");
    else
      asm volatile("s_waitcnt vmcnt(0)" ::: "memory");
    __builtin_amdgcn_s_barrier();
  };

  // ---- prologue: A(0),B(0),B(1) staged; vmcnt(4) drains tile 0
  stage(A, m0, sAbuf[0], 0, 0);
  stage(A, m0, sAbuf[0], 1, 0);
  stage(B, n0, sBbuf[0], 0, 0);
  stage(B, n0, sBbuf[0], 1, 0);
  if (NT > 1) {
    stage(B, n0, sBbuf[1], 0, 1);
    stage(B, n0, sBbuf[1], 1, 1);
    asm volatile("s_waitcnt vmcnt(4)" ::: "memory");
  } else {
    asm volatile("s_waitcnt vmcnt(0)" ::: "memory");
  }
  __builtin_amdgcn_s_barrier();

  // ---- main loop: static 2-tile unroll, named buffers (NT is even)
  for (int t = 0; t < NT; t += 2) {
    ktile(t, sAbuf[0], sBbuf[0], sAbuf[1]);
    ktile(t + 1, sAbuf[1], sBbuf[1], sAbuf[0]);
  }

  // ---- epilogue: C/D layout col=lane&15, row=(lane>>4)*4+reg (m89-verified)
  const int rb = m0 + wr * 128 + (lane >> 4) * 4;
  const int cb = n0 + wc * 64 + lrow;
#pragma unroll
  for (int mf = 0; mf < 8; ++mf) {
#pragma unroll
    for (int r = 0; r < 4; ++r) {
      const long rowoff = (long)(rb + mf * 16 + r) * N + cb;
#pragma unroll
      for (int n = 0; n < 4; ++n) {
        if (OUT_BF16)
          ((u16*)Cv)[rowoff + n * 16] = f2bf(acc[mf][n][r]);
        else
          ((float*)Cv)[rowoff + n * 16] = acc[mf][n][r];
      }
    }
  }
}

// ---------------- in-place LayerNorm over rows of 4096 ----------------
__global__ __launch_bounds__(256) void k_layernorm(
    float* __restrict__ h, const float* __restrict__ gamma,
    const float* __restrict__ beta) {
  const int H = 4096;
  float* p = h + (long)blockIdx.x * H;
  int t = threadIdx.x;
  float4 v[4];
  float sum = 0.f, sq = 0.f;
#pragma unroll
  for (int i = 0; i < 4; ++i) {
    v[i] = ((const float4*)p)[i * 256 + t];
    sum += v[i].x + v[i].y + v[i].z + v[i].w;
    sq += v[i].x * v[i].x + v[i].y * v[i].y + v[i].z * v[i].z + v[i].w * v[i].w;
  }
#pragma unroll
  for (int off = 32; off > 0; off >>= 1) {
    sum += __shfl_down(sum, off, 64);
    sq += __shfl_down(sq, off, 64);
  }
  __shared__ float ss[4], sg[4];
  if ((t & 63) == 0) { ss[t >> 6] = sum; sg[t >> 6] = sq; }
  __syncthreads();
  sum = ss[0] + ss[1] + ss[2] + ss[3];
  sq = sg[0] + sg[1] + sg[2] + sg[3];
  float mu = sum * (1.0f / H);
  float var = sq * (1.0f / H) - mu * mu;
  float rs = rsqrtf(var + 1e-5f);
#pragma unroll
  for (int i = 0; i < 4; ++i) {
    float4 g = ((const float4*)gamma)[i * 256 + t];
    float4 b = ((const float4*)beta)[i * 256 + t];
    float4 o;
    o.x = (v[i].x - mu) * rs * g.x + b.x;
    o.y = (v[i].y - mu) * rs * g.y + b.y;
    o.z = (v[i].z - mu) * rs * g.z + b.z;
    o.w = (v[i].w - mu) * rs * g.w + b.w;
    ((float4*)p)[i * 256 + t] = o;
  }
}

extern "C" void kernel_launch(void* const* d_in, const int* in_sizes, int n_in,
                              void* d_out, int out_size, void* d_ws,
                              size_t ws_size, hipStream_t stream) {
  const float* x      = (const float*)d_in[0];
  const float* w_a    = (const float*)d_in[1];
  const float* s_a    = (const float*)d_in[2];
  const float* w_b    = (const float*)d_in[3];
  const float* s_b    = (const float*)d_in[4];
  const float* w_proj = (const float*)d_in[5];
  const float* gamma  = (const float*)d_in[6];
  const float* beta   = (const float*)d_in[7];

  const int H = 4096, LO = 8192, SO = 2048, NR = 8192;
  const int KT = LO + SO;  // 10240

  char* ws = (char*)d_ws;
  u16* xb   = (u16*)(ws);                 // 64 MiB
  u16* wpb  = (u16*)(ws + 0x4000000L);    // 80 MiB
  u16* wqT  = (u16*)(ws + 0x9000000L);    // 80 MiB
  u16* weff = (u16*)(ws + 0xE000000L);    // 32 MiB
  float* h  = (float*)d_out;

  // 1. convert w_proj; quantize+transpose weights (GEMM1 operands first)
  k_f32_to_bf16<<<2048, 256, 0, stream>>>(w_proj, wpb, (long)H * KT);
  k_quant_transpose<<<dim3(LO / 64, H / 64), 256, 0, stream>>>(
      w_a, s_a, wqT, LO, H, H / 128, (long)KT, 0);
  k_quant_transpose<<<dim3(SO / 64, H / 64), 256, 0, stream>>>(
      w_b, s_b, wqT, SO, H, H / 128, (long)KT, LO);

  // 2. W_eff = w_proj @ Wq  -> bf16 [H][H]
  k_gemm8<true><<<(H / 256) * (H / 256), 512, 0, stream>>>(
      wpb, wqT, (void*)weff, H, H, KT);

  // 3. convert x (after GEMM1 so xb is LLC-hot for GEMM2)
  k_f32_to_bf16<<<2048, 256, 0, stream>>>(x, xb, (long)NR * H);

  // 4. h = x @ W_eff^T  -> fp32 into d_out
  k_gemm8<false><<<(NR / 256) * (H / 256), 512, 0, stream>>>(
      xb, weff, (void*)h, NR, H, H);

  // 5. LayerNorm in place
  k_layernorm<<<NR, 256, 0, stream>>>(h, gamma, beta);
}

// Round 13
// 702.170 us; speedup vs baseline: 1.7677x; 1.7677x over previous
//
#include <hip/hip_runtime.h>

// ---------------------------------------------------------------------------
// TwoBranchFork: out = LN( concat(x@q(w_a)^T, x@q(w_b)^T) @ w_proj^T )
// Reassociated: W_eff = w_proj @ [q(w_a); q(w_b)]  (4096x4096), h = x @ W_eff^T
// FINAL (= round-7 build, 704us, MfmaUtil 47.7, bank-conflicts 0):
//  - 256x256 tile, BK=64, 8 waves (2x4), 16x16x32 MFMA, gload_lds width-16
//  - T1 XCD swizzle, T2 LDS XOR swizzle (linear dest + pre-swizzled source)
//  - dense MFMA clusters: lgkmcnt(0)+sched_barrier(0) after each pre-MFMA
//    barrier; lgkmcnt(8) throttle before barrier on the 12-read phase
//  - static 2-K-tile unroll, named buffers; counted vmcnt(4) at tile end
// Post-r7 attempts all regressed (r8 read-balance −19us, r9 deeper prefetch
// −26us, r10/r12 register read-ahead → scratch spill, r11 small-tile
// occupancy −112us): acc=128 AGPR + ~124 VGPR leaves no register headroom
// for operand read-ahead at this tile size — the LDS-read/MFMA serialization
// floor (~52% MfmaUtil) is this structure's plain-HIP ceiling.
// ---------------------------------------------------------------------------

typedef unsigned int u32;
typedef unsigned short u16;
typedef __bf16 bf16x8 __attribute__((ext_vector_type(8)));
typedef float f32x4 __attribute__((ext_vector_type(4)));
typedef u16 u16x8 __attribute__((ext_vector_type(8)));

#define AS1 __attribute__((address_space(1)))
#define AS3 __attribute__((address_space(3)))

__device__ __forceinline__ u16 f2bf(float f) {
  u32 u = __float_as_uint(f);
  u32 r = (u + 0x7fffu + ((u >> 16) & 1u)) >> 16;  // RNE
  return (u16)r;
}

// fp8 e4m3fn quantize-dequantize via HW cvt (OCP format + RNE on gfx950)
__device__ __forceinline__ float q_e4m3(float v) {
  int p = __builtin_amdgcn_cvt_pk_fp8_f32(v, v, 0, false);
  return __builtin_amdgcn_cvt_f32_fp8(p, 0);
}

__device__ __forceinline__ void gload16(const void* g, void* l) {
  __builtin_amdgcn_global_load_lds((const AS1 u32*)g, (AS3 u32*)l, 16, 0, 0);
}

// ---------------- elementwise f32 -> bf16 ----------------
__global__ __launch_bounds__(256) void k_f32_to_bf16(
    const float* __restrict__ in, u16* __restrict__ out, long n) {
  long i0 = ((long)blockIdx.x * 256 + threadIdx.x) * 8;
  long stride = (long)gridDim.x * 256 * 8;
  for (long i = i0; i < n; i += stride) {
    float4 a = *(const float4*)(in + i);
    float4 b = *(const float4*)(in + i + 4);
    u16x8 o;
    o[0] = f2bf(a.x); o[1] = f2bf(a.y); o[2] = f2bf(a.z); o[3] = f2bf(a.w);
    o[4] = f2bf(b.x); o[5] = f2bf(b.y); o[6] = f2bf(b.z); o[7] = f2bf(b.w);
    *(u16x8*)(out + i) = o;
  }
}

// ---------------- quantize (fp8 rt) + transpose into wqT ----------------
__global__ __launch_bounds__(256) void k_quant_transpose(
    const float* __restrict__ w, const float* __restrict__ s,
    u16* __restrict__ oT, int J, int Kd, int sCols, long oStride, int oColOff) {
  __shared__ u16 tile[64][72];
  int j0 = blockIdx.x * 64;
  int k0 = blockIdx.y * 64;
  float sc = s[(j0 >> 7) * sCols + (k0 >> 7)];
  int t = threadIdx.x;
  int row = t >> 2, seg = t & 3;
  const float4* src = (const float4*)(w + (long)(j0 + row) * Kd + k0 + seg * 16);
  u16* dst = &tile[row][seg * 16];
#pragma unroll
  for (int ii = 0; ii < 4; ++ii) {
    float4 v = src[ii];
    dst[ii * 4 + 0] = f2bf(q_e4m3(v.x / sc) * sc);
    dst[ii * 4 + 1] = f2bf(q_e4m3(v.y / sc) * sc);
    dst[ii * 4 + 2] = f2bf(q_e4m3(v.z / sc) * sc);
    dst[ii * 4 + 3] = f2bf(q_e4m3(v.w / sc) * sc);
  }
  __syncthreads();
  int r = t >> 2, cs = t & 3;
  u16* op = oT + (long)(k0 + r) * oStride + oColOff + j0 + cs * 16;
  u16x8 o0, o1;
#pragma unroll
  for (int ii = 0; ii < 8; ++ii) o0[ii] = tile[cs * 16 + ii][r];
#pragma unroll
  for (int ii = 0; ii < 8; ++ii) o1[ii] = tile[cs * 16 + 8 + ii][r];
  *(u16x8*)op = o0;
  *(u16x8*)(op + 8) = o1;
}

// ---------------- 256x256 8-phase bf16 bt-GEMM: C = A[M,K] * B[N,K]^T -------
template <bool OUT_BF16>
__global__ __launch_bounds__(512, 2) void k_gemm8(
    const u16* __restrict__ A, const u16* __restrict__ B, void* __restrict__ Cv,
    int M, int N, int K) {
  __shared__ u16 sAbuf[2][256 * 64];
  __shared__ u16 sBbuf[2][256 * 64];

  const int tid = threadIdx.x;
  const int lane = tid & 63;
  const int wave = tid >> 6;
  const int wr = wave >> 2, wc = wave & 3;  // 2x4 wave grid, each 128x64 of C

  // T1: XCD-aware block swizzle (grid % 8 == 0 by construction)
  const int nwg = gridDim.x;
  const int wg = blockIdx.x;
  const int wgs = (wg & 7) * (nwg >> 3) + (wg >> 3);
  const int nbn = N >> 8;
  const int m0 = (wgs / nbn) << 8;
  const int n0 = (wgs % nbn) << 8;
  const int NT = K >> 6;  // even for all our shapes (64, 160)

  const int lrow = lane & 15;
  const int kslot = lane >> 4;       // 0..3: 8-elem k-slot within 64-col row
  const int st_row = lane >> 3;      // staging: row within the 8-row stripe
  const int st_slot = lane & 7;
  const int st_src = ((st_slot ^ st_row) * 8);  // T2 inverse-swizzled source

  f32x4 acc[8][4] = {};

  auto stage = [&](const u16* __restrict__ G, int row0, u16* lds, int half,
                   int kt) {
#pragma unroll
    for (int r = 0; r < 2; ++r) {
      int row = half * 128 + r * 64 + wave * 8 + st_row;
      const u16* g = G + (long)(row0 + row) * K + kt * 64 + st_src;
      u16* l = lds + row * 64 + st_slot * 8;
      gload16(g, l);
    }
  };
  // T2 swizzled LDS fragment reads (2-way max bank aliasing = free)
  auto ldA = [&](const u16* sa, int mh, int m, int ks) -> bf16x8 {
    int row = wr * 128 + mh * 64 + m * 16 + lrow;
    int slot = (ks * 4 + kslot) ^ (row & 7);
    return *(const bf16x8*)(sa + row * 64 + slot * 8);
  };
  auto ldB = [&](const u16* sb, int n, int ks) -> bf16x8 {
    int row = wc * 64 + n * 16 + lrow;
    int slot = (ks * 4 + kslot) ^ (row & 7);
    return *(const bf16x8*)(sb + row * 64 + slot * 8);
  };

  // one K-tile: 4 phases, template-exact waits. sa/sb = current buffers,
  // saN = A(t+1) dest (other parity), B(t+2) dest = sb (same parity).
  auto ktile = [&](int t, const u16* sa, const u16* sb, u16* saN) {
    bf16x8 a0[4][2], a1[4][2], bb[4][2];

    // ---- P1: ds x12 (a0 + b01), stage A0(t+1), lgkm throttle, bar,
    //          lgkm(0)+schedbar, Q1 mh0 x n01, bar
#pragma unroll
    for (int m = 0; m < 4; ++m)
#pragma unroll
      for (int ks = 0; ks < 2; ++ks) a0[m][ks] = ldA(sa, 0, m, ks);
#pragma unroll
    for (int n = 0; n < 2; ++n)
#pragma unroll
      for (int ks = 0; ks < 2; ++ks) bb[n][ks] = ldB(sb, n, ks);
    if (t + 1 < NT) stage(A, m0, saN, 0, t + 1);
    asm volatile("s_waitcnt lgkmcnt(8)");
    __builtin_amdgcn_s_barrier();
    asm volatile("s_waitcnt lgkmcnt(0)");
    __builtin_amdgcn_sched_barrier(0);
    __builtin_amdgcn_s_setprio(1);
#pragma unroll
    for (int m = 0; m < 4; ++m)
#pragma unroll
      for (int n = 0; n < 2; ++n)
#pragma unroll
        for (int ks = 0; ks < 2; ++ks)
          acc[m][n] = __builtin_amdgcn_mfma_f32_16x16x32_bf16(
              a0[m][ks], bb[n][ks], acc[m][n], 0, 0, 0);
    __builtin_amdgcn_s_setprio(0);
    __builtin_amdgcn_s_barrier();

    // ---- P2: ds x4 (b23), stage A1(t+1), bar, lgkm(0)+schedbar,
    //          Q2 mh0 x n23, bar
#pragma unroll
    for (int n = 2; n < 4; ++n)
#pragma unroll
      for (int ks = 0; ks < 2; ++ks) bb[n][ks] = ldB(sb, n, ks);
    if (t + 1 < NT) stage(A, m0, saN, 1, t + 1);
    __builtin_amdgcn_s_barrier();
    asm volatile("s_waitcnt lgkmcnt(0)");
    __builtin_amdgcn_sched_barrier(0);
    __builtin_amdgcn_s_setprio(1);
#pragma unroll
    for (int m = 0; m < 4; ++m)
#pragma unroll
      for (int n = 2; n < 4; ++n)
#pragma unroll
        for (int ks = 0; ks < 2; ++ks)
          acc[m][n] = __builtin_amdgcn_mfma_f32_16x16x32_bf16(
              a0[m][ks], bb[n][ks], acc[m][n], 0, 0, 0);
    __builtin_amdgcn_s_setprio(0);
    __builtin_amdgcn_s_barrier();

    // ---- P3: ds x8 (a1), stage B0(t+2) into current sb, bar,
    //          lgkm(0)+schedbar, Q3 mh1 x n23, bar
#pragma unroll
    for (int m = 0; m < 4; ++m)
#pragma unroll
      for (int ks = 0; ks < 2; ++ks) a1[m][ks] = ldA(sa, 1, m, ks);
    if (t + 2 < NT) stage(B, n0, (u16*)sb, 0, t + 2);
    __builtin_amdgcn_s_barrier();
    asm volatile("s_waitcnt lgkmcnt(0)");
    __builtin_amdgcn_sched_barrier(0);
    __builtin_amdgcn_s_setprio(1);
#pragma unroll
    for (int m = 0; m < 4; ++m)
#pragma unroll
      for (int n = 2; n < 4; ++n)
#pragma unroll
        for (int ks = 0; ks < 2; ++ks)
          acc[4 + m][n] = __builtin_amdgcn_mfma_f32_16x16x32_bf16(
              a1[m][ks], bb[n][ks], acc[4 + m][n], 0, 0, 0);
    __builtin_amdgcn_s_setprio(0);
    __builtin_amdgcn_s_barrier();

    // ---- P4: stage B1(t+2), bar, Q4 mh1 x n01 (pure MFMA), vmcnt, bar
    if (t + 2 < NT) stage(B, n0, (u16*)sb, 1, t + 2);
    __builtin_amdgcn_s_barrier();
    __builtin_amdgcn_s_setprio(1);
#pragma unroll
    for (int m = 0; m < 4; ++m)
#pragma unroll
      for (int n = 0; n < 2; ++n)
#pragma unroll
        for (int ks = 0; ks < 2; ++ks)
          acc[4 + m][n] = __builtin_amdgcn_mfma_f32_16x16x32_bf16(
              a1[m][ks], bb[n][ks], acc[4 + m][n], 0, 0, 0);
    __builtin_amdgcn_s_setprio(0);
    if (t + 2 < NT)
      asm volatile("s_waitcnt vmcnt(4)" ::: "memory");
    else
      asm volatile("s_waitcnt vmcnt(0)" ::: "memory");
    __builtin_amdgcn_s_barrier();
  };

  // ---- prologue: tile0 fully + tile1 B halves; wait tile0, keep 4 in flight
  stage(A, m0, sAbuf[0], 0, 0);
  stage(A, m0, sAbuf[0], 1, 0);
  stage(B, n0, sBbuf[0], 0, 0);
  stage(B, n0, sBbuf[0], 1, 0);
  if (NT > 1) {
    stage(B, n0, sBbuf[1], 0, 1);
    stage(B, n0, sBbuf[1], 1, 1);
    asm volatile("s_waitcnt vmcnt(4)" ::: "memory");
  } else {
    asm volatile("s_waitcnt vmcnt(0)" ::: "memory");
  }
  __builtin_amdgcn_s_barrier();

  // ---- main loop: static 2-tile unroll, named buffers (NT is even)
  for (int t = 0; t < NT; t += 2) {
    ktile(t, sAbuf[0], sBbuf[0], sAbuf[1]);
    ktile(t + 1, sAbuf[1], sBbuf[1], sAbuf[0]);
  }

  // ---- epilogue: C/D layout col=lane&15, row=(lane>>4)*4+reg (m89-verified)
  const int rb = m0 + wr * 128 + (lane >> 4) * 4;
  const int cb = n0 + wc * 64 + lrow;
#pragma unroll
  for (int mf = 0; mf < 8; ++mf) {
#pragma unroll
    for (int r = 0; r < 4; ++r) {
      const long rowoff = (long)(rb + mf * 16 + r) * N + cb;
#pragma unroll
      for (int n = 0; n < 4; ++n) {
        if (OUT_BF16)
          ((u16*)Cv)[rowoff + n * 16] = f2bf(acc[mf][n][r]);
        else
          ((float*)Cv)[rowoff + n * 16] = acc[mf][n][r];
      }
    }
  }
}

// ---------------- in-place LayerNorm over rows of 4096 ----------------
__global__ __launch_bounds__(256) void k_layernorm(
    float* __restrict__ h, const float* __restrict__ gamma,
    const float* __restrict__ beta) {
  const int H = 4096;
  float* p = h + (long)blockIdx.x * H;
  int t = threadIdx.x;
  float4 v[4];
  float sum = 0.f, sq = 0.f;
#pragma unroll
  for (int i = 0; i < 4; ++i) {
    v[i] = ((const float4*)p)[i * 256 + t];
    sum += v[i].x + v[i].y + v[i].z + v[i].w;
    sq += v[i].x * v[i].x + v[i].y * v[i].y + v[i].z * v[i].z + v[i].w * v[i].w;
  }
#pragma unroll
  for (int off = 32; off > 0; off >>= 1) {
    sum += __shfl_down(sum, off, 64);
    sq += __shfl_down(sq, off, 64);
  }
  __shared__ float ss[4], sg[4];
  if ((t & 63) == 0) { ss[t >> 6] = sum; sg[t >> 6] = sq; }
  __syncthreads();
  sum = ss[0] + ss[1] + ss[2] + ss[3];
  sq = sg[0] + sg[1] + sg[2] + sg[3];
  float mu = sum * (1.0f / H);
  float var = sq * (1.0f / H) - mu * mu;
  float rs = rsqrtf(var + 1e-5f);
#pragma unroll
  for (int i = 0; i < 4; ++i) {
    float4 g = ((const float4*)gamma)[i * 256 + t];
    float4 b = ((const float4*)beta)[i * 256 + t];
    float4 o;
    o.x = (v[i].x - mu) * rs * g.x + b.x;
    o.y = (v[i].y - mu) * rs * g.y + b.y;
    o.z = (v[i].z - mu) * rs * g.z + b.z;
    o.w = (v[i].w - mu) * rs * g.w + b.w;
    ((float4*)p)[i * 256 + t] = o;
  }
}

extern "C" void kernel_launch(void* const* d_in, const int* in_sizes, int n_in,
                              void* d_out, int out_size, void* d_ws,
                              size_t ws_size, hipStream_t stream) {
  const float* x      = (const float*)d_in[0];
  const float* w_a    = (const float*)d_in[1];
  const float* s_a    = (const float*)d_in[2];
  const float* w_b    = (const float*)d_in[3];
  const float* s_b    = (const float*)d_in[4];
  const float* w_proj = (const float*)d_in[5];
  const float* gamma  = (const float*)d_in[6];
  const float* beta   = (const float*)d_in[7];

  const int H = 4096, LO = 8192, SO = 2048, NR = 8192;
  const int KT = LO + SO;  // 10240

  char* ws = (char*)d_ws;
  u16* xb   = (u16*)(ws);                 // 64 MiB
  u16* wpb  = (u16*)(ws + 0x4000000L);    // 80 MiB
  u16* wqT  = (u16*)(ws + 0x9000000L);    // 80 MiB
  u16* weff = (u16*)(ws + 0xE000000L);    // 32 MiB
  float* h  = (float*)d_out;

  // 1. convert w_proj; quantize+transpose weights (GEMM1 operands first)
  k_f32_to_bf16<<<2048, 256, 0, stream>>>(w_proj, wpb, (long)H * KT);
  k_quant_transpose<<<dim3(LO / 64, H / 64), 256, 0, stream>>>(
      w_a, s_a, wqT, LO, H, H / 128, (long)KT, 0);
  k_quant_transpose<<<dim3(SO / 64, H / 64), 256, 0, stream>>>(
      w_b, s_b, wqT, SO, H, H / 128, (long)KT, LO);

  // 2. W_eff = w_proj @ Wq  -> bf16 [H][H]
  k_gemm8<true><<<(H / 256) * (H / 256), 512, 0, stream>>>(
      wpb, wqT, (void*)weff, H, H, KT);

  // 3. convert x (after GEMM1 so xb is LLC-hot for GEMM2)
  k_f32_to_bf16<<<2048, 256, 0, stream>>>(x, xb, (long)NR * H);

  // 4. h = x @ W_eff^T  -> fp32 into d_out
  k_gemm8<false><<<(NR / 256) * (H / 256), 512, 0, stream>>>(
      xb, weff, (void*)h, NR, H, H);

  // 5. LayerNorm in place
  k_layernorm<<<NR, 256, 0, stream>>>(h, gamma, beta);
}